// Round 2
// baseline (1122.783 us; speedup 1.0000x reference)
//
#include <hip/hip_runtime.h>
#include <hip/hip_cooperative_groups.h>
#include <math.h>

namespace cg = cooperative_groups;

#define BSZ 128
#define NN_ 4096
#define MM_ 64
#define HH_ 512
#define EPSF 1e-8f

__device__ __forceinline__ float sigmoidf_(float x) { return 1.0f / (1.0f + expf(-x)); }
__device__ __forceinline__ float softplusf_(float x) { return fmaxf(x, 0.0f) + log1pf(expf(-fabsf(x))); }

// ------------------------------------------------------------------
// gates[128,2048] += [in_data|prev_reads|h_prev][128,1024] @ [W_ih|W_hh][2048,1024]^T
// split-K over grid.y (16 slices of 64), atomic accumulate
__global__ __launch_bounds__(256) void k_gemm_gates(const float* __restrict__ in_data,
                                                    const float* __restrict__ prev_reads,
                                                    const float* __restrict__ h_prev,
                                                    const float* __restrict__ W_ih,
                                                    const float* __restrict__ W_hh,
                                                    float* __restrict__ C) {
    __shared__ float Alds[64 * 129];
    __shared__ float Wlds[64 * 65];
    int t = threadIdx.x;
    int k0 = blockIdx.y * 64;
    int n0 = blockIdx.x * 64;
    for (int i = 0; i < 8; ++i) {
        int f = t + 256 * i;
        int row = f >> 4, kk = (f & 15) * 4;
        int k = k0 + kk;
        float4 v;
        if (k < 256) v = *(const float4*)(in_data + (row << 8) + k);
        else if (k < 512) {
            int q = k - 256;
            v = *(const float4*)(prev_reads + (((q >> 6) * BSZ + row) << 6) + (q & 63));
        } else v = *(const float4*)(h_prev + (row << 9) + (k - 512));
        Alds[(kk + 0) * 129 + row] = v.x;
        Alds[(kk + 1) * 129 + row] = v.y;
        Alds[(kk + 2) * 129 + row] = v.z;
        Alds[(kk + 3) * 129 + row] = v.w;
    }
    for (int i = 0; i < 4; ++i) {
        int f = t + 256 * i;
        int o = f >> 4, kk = (f & 15) * 4;
        int j = n0 + o, k = k0 + kk;
        const float* src = (k < 512) ? (W_ih + (size_t)j * 512 + k)
                                     : (W_hh + (size_t)j * 512 + (k - 512));
        float4 v = *(const float4*)src;
        Wlds[(kk + 0) * 65 + o] = v.x;
        Wlds[(kk + 1) * 65 + o] = v.y;
        Wlds[(kk + 2) * 65 + o] = v.z;
        Wlds[(kk + 3) * 65 + o] = v.w;
    }
    __syncthreads();
    int ob = (t & 15) * 4;
    int bb = (t >> 4) * 8;
    float acc[4][8];
#pragma unroll
    for (int i = 0; i < 4; ++i)
#pragma unroll
        for (int j = 0; j < 8; ++j) acc[i][j] = 0.f;
    for (int kk = 0; kk < 64; ++kk) {
        const float* wp = &Wlds[kk * 65 + ob];
        const float* ap = &Alds[kk * 129 + bb];
        float w0 = wp[0], w1 = wp[1], w2 = wp[2], w3 = wp[3];
#pragma unroll
        for (int j = 0; j < 8; ++j) {
            float av = ap[j];
            acc[0][j] = fmaf(w0, av, acc[0][j]);
            acc[1][j] = fmaf(w1, av, acc[1][j]);
            acc[2][j] = fmaf(w2, av, acc[2][j]);
            acc[3][j] = fmaf(w3, av, acc[3][j]);
        }
    }
#pragma unroll
    for (int i = 0; i < 4; ++i)
#pragma unroll
        for (int j = 0; j < 8; ++j)
            atomicAdd(&C[(size_t)(bb + j) * 2048 + n0 + ob + i], acc[i][j]);
}

// ------------------------------------------------------------------
// Chead[128,1408] += cbuf[128,512] @ Whead[1408,512]^T   (rows gathered from
// the 7 live heads' parameter arrays; rows >=1386 are zero pad)
__device__ __forceinline__ const float* whead_row_ptr(const float* Wk, const float* Wbeta,
                                                      const float* Wg, const float* Ws,
                                                      const float* Wgam, const float* We,
                                                      const float* Wa, int r) {
    int i = r / 198, q = r - i * 198;
    if (q < 64)  return Wk + (size_t)((i << 6) + q) * 512;
    if (q == 64) return Wbeta + (size_t)i * 512;
    if (q == 65) return Wg + (size_t)i * 512;
    if (q <= 68) return Ws + (size_t)(i * 3 + q - 66) * 512;
    if (q == 69) return Wgam + (size_t)i * 512;
    if (q < 134) return We + (size_t)((i << 6) + q - 70) * 512;
    return Wa + (size_t)((i << 6) + q - 134) * 512;
}

__global__ __launch_bounds__(256) void k_gemm_head(const float* __restrict__ A,
                                                   const float* __restrict__ Wk,
                                                   const float* __restrict__ Wbeta,
                                                   const float* __restrict__ Wg,
                                                   const float* __restrict__ Ws,
                                                   const float* __restrict__ Wgam,
                                                   const float* __restrict__ We,
                                                   const float* __restrict__ Wa,
                                                   float* __restrict__ C) {
    __shared__ float Alds[64 * 129];
    __shared__ float Wlds[64 * 65];
    int t = threadIdx.x;
    int k0 = blockIdx.y * 64;
    int n0 = blockIdx.x * 64;
    for (int i = 0; i < 8; ++i) {
        int f = t + 256 * i;
        int row = f >> 4, kk = (f & 15) * 4;
        float4 v = *(const float4*)(A + (size_t)row * 512 + k0 + kk);
        Alds[(kk + 0) * 129 + row] = v.x;
        Alds[(kk + 1) * 129 + row] = v.y;
        Alds[(kk + 2) * 129 + row] = v.z;
        Alds[(kk + 3) * 129 + row] = v.w;
    }
    for (int i = 0; i < 4; ++i) {
        int f = t + 256 * i;
        int o = f >> 4, kk = (f & 15) * 4;
        int r = n0 + o;
        float4 v = make_float4(0.f, 0.f, 0.f, 0.f);
        if (r < 1386) {
            const float* p = whead_row_ptr(Wk, Wbeta, Wg, Ws, Wgam, We, Wa, r) + k0 + kk;
            v = *(const float4*)p;
        }
        Wlds[(kk + 0) * 65 + o] = v.x;
        Wlds[(kk + 1) * 65 + o] = v.y;
        Wlds[(kk + 2) * 65 + o] = v.z;
        Wlds[(kk + 3) * 65 + o] = v.w;
    }
    __syncthreads();
    int ob = (t & 15) * 4;
    int bb = (t >> 4) * 8;
    float acc[4][8];
#pragma unroll
    for (int i = 0; i < 4; ++i)
#pragma unroll
        for (int j = 0; j < 8; ++j) acc[i][j] = 0.f;
    for (int kk = 0; kk < 64; ++kk) {
        const float* wp = &Wlds[kk * 65 + ob];
        const float* ap = &Alds[kk * 129 + bb];
        float w0 = wp[0], w1 = wp[1], w2 = wp[2], w3 = wp[3];
#pragma unroll
        for (int j = 0; j < 8; ++j) {
            float av = ap[j];
            acc[0][j] = fmaf(w0, av, acc[0][j]);
            acc[1][j] = fmaf(w1, av, acc[1][j]);
            acc[2][j] = fmaf(w2, av, acc[2][j]);
            acc[3][j] = fmaf(w3, av, acc[3][j]);
        }
    }
#pragma unroll
    for (int i = 0; i < 4; ++i)
#pragma unroll
        for (int j = 0; j < 8; ++j)
            atomicAdd(&C[(size_t)(bb + j) * 1408 + n0 + ob + i], acc[i][j]);
}

// ------------------------------------------------------------------
__global__ void k_lstm(const float* __restrict__ gates, const float* __restrict__ b_ih,
                       const float* __restrict__ b_hh, const float* __restrict__ c_prev,
                       float* __restrict__ cbuf, float* __restrict__ hbuf) {
    int idx = blockIdx.x * blockDim.x + threadIdx.x;
    if (idx >= BSZ * HH_) return;
    int b = idx >> 9, j = idx & 511;
    const float* gr = gates + (size_t)b * 2048;
    float gi = gr[j]        + b_ih[j]        + b_hh[j];
    float gf = gr[512 + j]  + b_ih[512 + j]  + b_hh[512 + j];
    float gg = gr[1024 + j] + b_ih[1024 + j] + b_hh[1024 + j];
    float go = gr[1536 + j] + b_ih[1536 + j] + b_hh[1536 + j];
    float cc = sigmoidf_(gf) * c_prev[idx] + sigmoidf_(gi) * tanhf(gg);
    float hh = sigmoidf_(go) * tanhf(cc);
    cbuf[idx] = cc;
    hbuf[idx] = hh;
}

// ------------------------------------------------------------------
// per (head<7, b): bias-add + activations on the head-parameter row
__global__ __launch_bounds__(256) void k_headact(const float* __restrict__ Chead,
                                                 const float* __restrict__ bk, const float* __restrict__ bbeta,
                                                 const float* __restrict__ bg, const float* __restrict__ bs,
                                                 const float* __restrict__ bgam, const float* __restrict__ be,
                                                 const float* __restrict__ ba,
                                                 float* __restrict__ keys, float* __restrict__ knorm,
                                                 float* __restrict__ betaA, float* __restrict__ gA,
                                                 float* __restrict__ gammaA, float* __restrict__ sA,
                                                 float* __restrict__ eA, float* __restrict__ aA) {
    __shared__ float sk[64];
    __shared__ float s3[3];
    int blk = blockIdx.x;
    int i = blk >> 7, b = blk & 127;
    int q = threadIdx.x;
    float val = 0.f;
    if (q < 198) {
        float bv = (q < 64)   ? bk[(i << 6) + q]
                 : (q == 64)  ? bbeta[i]
                 : (q == 65)  ? bg[i]
                 : (q <= 68)  ? bs[i * 3 + q - 66]
                 : (q == 69)  ? bgam[i]
                 : (q < 134)  ? be[(i << 6) + q - 70]
                              : ba[(i << 6) + q - 134];
        val = Chead[(size_t)b * 1408 + i * 198 + q] + bv;
    }
    if (q < 64) { keys[(size_t)(i * BSZ + b) * 64 + q] = val; sk[q] = val * val; }
    if (q >= 66 && q <= 68) s3[q - 66] = val;
    __syncthreads();
    if (q == 0) {
        float s = 0.f;
        for (int m2 = 0; m2 < 64; ++m2) s += sk[m2];
        knorm[i * BSZ + b] = sqrtf(s);
    }
    if (q == 64) betaA[i * BSZ + b] = softplusf_(val);
    if (q == 65) gA[i * BSZ + b] = sigmoidf_(val);
    if (q == 69) gammaA[i * BSZ + b] = 1.f + softplusf_(val);
    if (q == 66) {
        float mx = fmaxf(s3[0], fmaxf(s3[1], s3[2]));
        float e0 = expf(s3[0] - mx), e1 = expf(s3[1] - mx), e2 = expf(s3[2] - mx);
        float inv = 1.f / (e0 + e1 + e2);
        sA[(i * BSZ + b) * 3 + 0] = e0 * inv;
        sA[(i * BSZ + b) * 3 + 1] = e1 * inv;
        sA[(i * BSZ + b) * 3 + 2] = e2 * inv;
    }
    if (q >= 70 && q < 134)  eA[(size_t)(i * BSZ + b) * 64 + (q - 70)] = sigmoidf_(val);
    if (q >= 134 && q < 198) aA[(size_t)(i * BSZ + b) * 64 + (q - 134)] = tanhf(val);
}

// ------------------------------------------------------------------
// device sweep: grid-strided version of the read-only memory pass
__device__ __forceinline__ void dev_sweep(const float* __restrict__ mem,
                                          const float* __restrict__ wbuf,
                                          const float* __restrict__ eA, const float* __restrict__ aA,
                                          const float* __restrict__ keys, const float* __restrict__ knorm,
                                          float* __restrict__ sims, float* __restrict__ r_out,
                                          float* smem,
                                          int napply, int nsims, int sh0, int sh1,
                                          int read_state, int read_head, int read_idx) {
    int t = threadIdx.x;
    int lane = t & 15, grp = t >> 4;
    int m4 = lane * 4;
    const float* w1p = wbuf + (size_t)1 * BSZ * NN_;
    const float* w3p = wbuf + (size_t)3 * BSZ * NN_;
    const float* w5p = wbuf + (size_t)5 * BSZ * NN_;
    const float* wrp = (read_head >= 0) ? (wbuf + (size_t)read_head * BSZ * NN_) : nullptr;
    float* sim0 = sims + (size_t)sh0 * BSZ * NN_;
    float* sim1 = sims + (size_t)sh1 * BSZ * NN_;
    const int NVB = BSZ * NN_ / 64;   // 8192 virtual blocks
    for (int vb = blockIdx.x; vb < NVB; vb += gridDim.x) {
        int base = vb * 64;
        int b = base >> 12;
        float4 e1 = *(const float4*)(eA + (size_t)(1 * BSZ + b) * 64 + m4);
        float4 a1 = *(const float4*)(aA + (size_t)(1 * BSZ + b) * 64 + m4);
        float4 e3 = *(const float4*)(eA + (size_t)(3 * BSZ + b) * 64 + m4);
        float4 a3 = *(const float4*)(aA + (size_t)(3 * BSZ + b) * 64 + m4);
        float4 e5 = *(const float4*)(eA + (size_t)(5 * BSZ + b) * 64 + m4);
        float4 a5 = *(const float4*)(aA + (size_t)(5 * BSZ + b) * 64 + m4);
        float4 k0v = make_float4(0.f, 0.f, 0.f, 0.f), k1v = k0v;
        float kn0v = 0.f, kn1v = 0.f;
        if (nsims > 0) { k0v = *(const float4*)(keys + (size_t)(sh0 * BSZ + b) * 64 + m4); kn0v = knorm[sh0 * BSZ + b]; }
        if (nsims > 1) { k1v = *(const float4*)(keys + (size_t)(sh1 * BSZ + b) * 64 + m4); kn1v = knorm[sh1 * BSZ + b]; }
        float4 racc = make_float4(0.f, 0.f, 0.f, 0.f);
        for (int it = 0; it < 4; ++it) {
            int row = base + it * 16 + grp;
            float4 m = *(const float4*)(mem + (size_t)row * 64 + m4);
            float4 mr = m;
            if (napply >= 1) {
                float w = w1p[row];
                m.x = m.x * (1.f - w * e1.x) + w * a1.x;
                m.y = m.y * (1.f - w * e1.y) + w * a1.y;
                m.z = m.z * (1.f - w * e1.z) + w * a1.z;
                m.w = m.w * (1.f - w * e1.w) + w * a1.w;
                if (read_state == 1) mr = m;
            }
            if (napply >= 2) {
                float w = w3p[row];
                m.x = m.x * (1.f - w * e3.x) + w * a3.x;
                m.y = m.y * (1.f - w * e3.y) + w * a3.y;
                m.z = m.z * (1.f - w * e3.z) + w * a3.z;
                m.w = m.w * (1.f - w * e3.w) + w * a3.w;
                if (read_state == 2) mr = m;
            }
            if (napply >= 3) {
                float w = w5p[row];
                m.x = m.x * (1.f - w * e5.x) + w * a5.x;
                m.y = m.y * (1.f - w * e5.y) + w * a5.y;
                m.z = m.z * (1.f - w * e5.z) + w * a5.z;
                m.w = m.w * (1.f - w * e5.w) + w * a5.w;
                if (read_state == 3) mr = m;
            }
            if (read_head >= 0) {
                float wr = wrp[row];
                racc.x = fmaf(wr, mr.x, racc.x);
                racc.y = fmaf(wr, mr.y, racc.y);
                racc.z = fmaf(wr, mr.z, racc.z);
                racc.w = fmaf(wr, mr.w, racc.w);
            }
            if (nsims > 0) {
                float d0 = m.x * k0v.x + m.y * k0v.y + m.z * k0v.z + m.w * k0v.w;
                float nn = m.x * m.x + m.y * m.y + m.z * m.z + m.w * m.w;
                float d1 = 0.f;
                if (nsims > 1) d1 = m.x * k1v.x + m.y * k1v.y + m.z * k1v.z + m.w * k1v.w;
#pragma unroll
                for (int off = 8; off >= 1; off >>= 1) {
                    d0 += __shfl_xor(d0, off, 16);
                    nn += __shfl_xor(nn, off, 16);
                    if (nsims > 1) d1 += __shfl_xor(d1, off, 16);
                }
                if (lane == 0) {
                    float nm = sqrtf(nn);
                    sim0[row] = d0 / (nm * kn0v + EPSF);
                    if (nsims > 1) sim1[row] = d1 / (nm * kn1v + EPSF);
                }
            }
        }
        if (read_head >= 0) {
            *(float4*)(&smem[grp * 64 + m4]) = racc;
            __syncthreads();
            if (t < 64) {
                float s = 0.f;
#pragma unroll
                for (int g2 = 0; g2 < 16; ++g2) s += smem[g2 * 64 + t];
                atomicAdd(&r_out[(size_t)(read_idx * BSZ + b) * 64 + t], s);
            }
            __syncthreads();   // protect smem before next virtual block
        }
    }
}

// ------------------------------------------------------------------
// device weights: per (head, b) softmax(beta*sim) -> interpolate -> shift ->
// sharpen -> normalize.  256 threads, 16 elems/thread, wave-shuffle reductions.
__device__ __forceinline__ void dev_weights(const float* __restrict__ sims,
                                            const float* __restrict__ prev_w,
                                            const float* __restrict__ betaA, const float* __restrict__ gA,
                                            const float* __restrict__ gammaA, const float* __restrict__ sA,
                                            float* __restrict__ wout_base, float* smem,
                                            int head0, int nheads) {
    float* wg = smem;            // 4096 floats
    float* red = smem + 4096;    // 16 floats
    int t = threadIdx.x, wv = t >> 6, ln = t & 63;
    int npairs = nheads * BSZ;
    for (int p = blockIdx.x; p < npairs; p += gridDim.x) {
        int h = head0 + (p >> 7), b = p & 127;
        int hb = h * BSZ + b;
        float beta = betaA[hb], g = gA[hb], gamma = gammaA[hb];
        float s0 = sA[hb * 3 + 0], s1 = sA[hb * 3 + 1], s2 = sA[hb * 3 + 2];
        const float* sim = sims + (size_t)hb * NN_;
        const float* pw = prev_w + (size_t)hb * NN_;
        float* wout = wout_base + (size_t)hb * NN_;
        float tv[16];
        float lmax = -3.4e38f;
#pragma unroll
        for (int j = 0; j < 16; ++j) {
            float x = beta * sim[t + 256 * j];
            tv[j] = x;
            lmax = fmaxf(lmax, x);
        }
#pragma unroll
        for (int off = 32; off >= 1; off >>= 1) lmax = fmaxf(lmax, __shfl_xor(lmax, off));
        if (ln == 0) red[wv] = lmax;
        __syncthreads();
        float Mx = fmaxf(fmaxf(red[0], red[1]), fmaxf(red[2], red[3]));
        float lsum = 0.f;
#pragma unroll
        for (int j = 0; j < 16; ++j) { float ex = expf(tv[j] - Mx); tv[j] = ex; lsum += ex; }
#pragma unroll
        for (int off = 32; off >= 1; off >>= 1) lsum += __shfl_xor(lsum, off);
        if (ln == 0) red[4 + wv] = lsum;
        __syncthreads();
        float invS = 1.f / (red[4] + red[5] + red[6] + red[7]);
#pragma unroll
        for (int j = 0; j < 16; ++j) {
            int n = t + 256 * j;
            wg[n] = g * tv[j] * invS + (1.f - g) * pw[n];
        }
        __syncthreads();
        float lsum2 = 0.f;
#pragma unroll
        for (int j = 0; j < 16; ++j) {
            int n = t + 256 * j;
            float wsft = s0 * wg[(n + 1) & (NN_ - 1)] + s1 * wg[n] + s2 * wg[(n - 1) & (NN_ - 1)];
            float wp = powf(wsft, gamma);
            tv[j] = wp;
            lsum2 += wp;
        }
#pragma unroll
        for (int off = 32; off >= 1; off >>= 1) lsum2 += __shfl_xor(lsum2, off);
        if (ln == 0) red[8 + wv] = lsum2;
        __syncthreads();
        float inv2 = 1.f / (red[8] + red[9] + red[10] + red[11] + EPSF);
#pragma unroll
        for (int j = 0; j < 16; ++j) wout[t + 256 * j] = tv[j] * inv2;
        __syncthreads();   // protect wg/red before next pair
    }
}

// ------------------------------------------------------------------
// cooperative mega-kernel: 5 sweeps + 4 weight phases, grid.sync between
__global__ __launch_bounds__(256) void k_mega(const float* __restrict__ mem,
                                              float* __restrict__ wbuf,
                                              const float* __restrict__ eA, const float* __restrict__ aA,
                                              const float* __restrict__ keys, const float* __restrict__ knorm,
                                              float* __restrict__ sims, float* __restrict__ r_out,
                                              const float* __restrict__ prev_w,
                                              const float* __restrict__ betaA, const float* __restrict__ gA,
                                              const float* __restrict__ gammaA, const float* __restrict__ sA) {
    cg::grid_group grid = cg::this_grid();
    __shared__ float smem[4096 + 16];
    // S0: sims heads 0,1 on mem0
    dev_sweep(mem, wbuf, eA, aA, keys, knorm, sims, r_out, smem, 0, 2, 0, 1, -1, -1, 0);
    grid.sync();
    dev_weights(sims, prev_w, betaA, gA, gammaA, sA, wbuf, smem, 0, 2);
    grid.sync();
    // S1: sims heads 2,3 on mem1 (apply w1); r0 from mem0
    dev_sweep(mem, wbuf, eA, aA, keys, knorm, sims, r_out, smem, 1, 2, 2, 3, 0, 0, 0);
    grid.sync();
    dev_weights(sims, prev_w, betaA, gA, gammaA, sA, wbuf, smem, 2, 2);
    grid.sync();
    // S2: sims heads 4,5 on mem2 (apply w1,w3); r2 from mem1
    dev_sweep(mem, wbuf, eA, aA, keys, knorm, sims, r_out, smem, 2, 2, 4, 5, 1, 2, 1);
    grid.sync();
    dev_weights(sims, prev_w, betaA, gA, gammaA, sA, wbuf, smem, 4, 2);
    grid.sync();
    // S3: sim head 6 on mem3 (apply w1,w3,w5); r4 from mem2
    dev_sweep(mem, wbuf, eA, aA, keys, knorm, sims, r_out, smem, 3, 1, 6, 6, 2, 4, 2);
    grid.sync();
    dev_weights(sims, prev_w, betaA, gA, gammaA, sA, wbuf, smem, 6, 1);
    grid.sync();
    // S4: r6 from mem3; head 7 dead
    dev_sweep(mem, wbuf, eA, aA, keys, knorm, sims, r_out, smem, 3, 0, 0, 0, 3, 6, 3);
}

// ------------------------------------------------------------------
// out[128,256] = sigmoid([hbuf|rbuf][128,768] @ W_out[256,768]^T + b_out)
// full-K (no atomics): grid = (4 n-tiles, 2 b-tiles)
__global__ __launch_bounds__(256) void k_out_full(const float* __restrict__ hbuf,
                                                  const float* __restrict__ rbuf,
                                                  const float* __restrict__ W_out,
                                                  const float* __restrict__ b_out,
                                                  float* __restrict__ out) {
    __shared__ float Alds[64 * 65];
    __shared__ float Wlds[64 * 65];
    int t = threadIdx.x;
    int n0 = blockIdx.x * 64;
    int b0 = blockIdx.y * 64;
    int ob = (t & 15) * 4;
    int bb = (t >> 4) * 4;
    float acc[4][4];
#pragma unroll
    for (int i = 0; i < 4; ++i)
#pragma unroll
        for (int j = 0; j < 4; ++j) acc[i][j] = 0.f;
    for (int k0 = 0; k0 < 768; k0 += 64) {
        __syncthreads();
        for (int i = 0; i < 4; ++i) {
            int f = t + 256 * i;
            int rb = f >> 4, kk = (f & 15) * 4;
            int k = k0 + kk;
            float4 v;
            if (k < 512) v = *(const float4*)(hbuf + ((b0 + rb) << 9) + k);
            else {
                int q = k - 512;
                v = *(const float4*)(rbuf + (((q >> 6) * BSZ + b0 + rb) << 6) + (q & 63));
            }
            Alds[(kk + 0) * 65 + rb] = v.x;
            Alds[(kk + 1) * 65 + rb] = v.y;
            Alds[(kk + 2) * 65 + rb] = v.z;
            Alds[(kk + 3) * 65 + rb] = v.w;
        }
        for (int i = 0; i < 4; ++i) {
            int f = t + 256 * i;
            int o = f >> 4, kk = (f & 15) * 4;
            float4 v = *(const float4*)(W_out + (size_t)(n0 + o) * 768 + k0 + kk);
            Wlds[(kk + 0) * 65 + o] = v.x;
            Wlds[(kk + 1) * 65 + o] = v.y;
            Wlds[(kk + 2) * 65 + o] = v.z;
            Wlds[(kk + 3) * 65 + o] = v.w;
        }
        __syncthreads();
        for (int kk = 0; kk < 64; ++kk) {
            const float* wp = &Wlds[kk * 65 + ob];
            const float* ap = &Alds[kk * 65 + bb];
            float w0 = wp[0], w1 = wp[1], w2 = wp[2], w3 = wp[3];
#pragma unroll
            for (int j = 0; j < 4; ++j) {
                float av = ap[j];
                acc[0][j] = fmaf(w0, av, acc[0][j]);
                acc[1][j] = fmaf(w1, av, acc[1][j]);
                acc[2][j] = fmaf(w2, av, acc[2][j]);
                acc[3][j] = fmaf(w3, av, acc[3][j]);
            }
        }
    }
#pragma unroll
    for (int i = 0; i < 4; ++i)
#pragma unroll
        for (int j = 0; j < 4; ++j)
            out[(size_t)(b0 + bb + j) * 256 + n0 + ob + i] = sigmoidf_(acc[i][j] + b_out[n0 + ob + i]);
}

// ------------------------------------------------------------------
extern "C" void kernel_launch(void* const* d_in, const int* in_sizes, int n_in,
                              void* d_out, int out_size, void* d_ws, size_t ws_size,
                              hipStream_t stream) {
    const float* in_data      = (const float*)d_in[0];
    const float* memory       = (const float*)d_in[1];   // READ-ONLY
    const float* h_prev       = (const float*)d_in[2];
    const float* c_prev       = (const float*)d_in[3];
    const float* prev_reads   = (const float*)d_in[4];
    const float* prev_weights = (const float*)d_in[5];
    const float* W_ih = (const float*)d_in[6];
    const float* b_ih = (const float*)d_in[7];
    const float* W_hh = (const float*)d_in[8];
    const float* b_hh = (const float*)d_in[9];
    const float* W_out = (const float*)d_in[10];
    const float* b_out = (const float*)d_in[11];
    const float* Wk   = (const float*)d_in[12];
    const float* bk   = (const float*)d_in[13];
    const float* Wbeta = (const float*)d_in[14];
    const float* bbeta = (const float*)d_in[15];
    const float* Wg   = (const float*)d_in[16];
    const float* bg   = (const float*)d_in[17];
    const float* Ws   = (const float*)d_in[18];
    const float* bs   = (const float*)d_in[19];
    const float* Wgam = (const float*)d_in[20];
    const float* bgam = (const float*)d_in[21];
    const float* We   = (const float*)d_in[22];
    const float* be   = (const float*)d_in[23];
    const float* Wa   = (const float*)d_in[24];
    const float* ba   = (const float*)d_in[25];

    float* ws = (float*)d_ws;
    // zero-init region (atomic accumulators)
    size_t o_gates  = 0;                        // [128,2048] = 262144
    size_t o_chead  = o_gates + 262144;         // [128,1408] = 180224
    size_t o_r      = o_chead + 180224;         // [4,128,64] = 32768
    size_t zero_floats = o_r + 32768;           // 475136 floats ~ 1.9 MB
    // non-zeroed scratch
    size_t o_c     = zero_floats;               // [128,512]
    size_t o_h     = o_c + 65536;               // [128,512]
    size_t o_keys  = o_h + 65536;               // [7,128,64] = 57344
    size_t o_knorm = o_keys + 57344;            // [7,128] pad 1024
    size_t o_beta  = o_knorm + 1024;
    size_t o_g     = o_beta + 1024;
    size_t o_gamma = o_g + 1024;
    size_t o_s     = o_gamma + 1024;            // [7,128,3] pad 3072
    size_t o_e     = o_s + 3072;                // [7,128,64] = 57344
    size_t o_a     = o_e + 57344;
    size_t o_sims  = o_a + 57344;               // [7,128,4096] = 3670016
    size_t o_w     = o_sims + 3670016;          // [7,128,4096] = 3670016

    float* gates  = ws + o_gates;
    float* Chead  = ws + o_chead;
    float* rbuf   = ws + o_r;
    float* cbuf   = ws + o_c;
    float* hbuf   = ws + o_h;
    float* keys   = ws + o_keys;
    float* knorm  = ws + o_knorm;
    float* betaA  = ws + o_beta;
    float* gA     = ws + o_g;
    float* gammaA = ws + o_gamma;
    float* sA     = ws + o_s;
    float* eA     = ws + o_e;
    float* aA     = ws + o_a;
    float* sims   = ws + o_sims;
    float* wbuf   = ws + o_w;

    // cooperative grid size: all blocks co-resident (computed once)
    static int g_grid = 0;
    if (g_grid == 0) {
        int dev = 0;
        hipGetDevice(&dev);
        int ncu = 0;
        hipDeviceGetAttribute(&ncu, hipDeviceAttributeMultiprocessorCount, dev);
        int maxb = 0;
        hipOccupancyMaxActiveBlocksPerMultiprocessor(&maxb, k_mega, 256, 0);
        if (ncu <= 0) ncu = 256;
        if (maxb <= 0) maxb = 1;
        g_grid = ncu * maxb;
        if (g_grid > 8192) g_grid = 8192;
    }

    hipMemsetAsync(d_ws, 0, zero_floats * sizeof(float), stream);

    // controller LSTM (fused concat + both GEMMs, K=1024 split over 16 slices)
    k_gemm_gates<<<dim3(32, 16), 256, 0, stream>>>(in_data, prev_reads, h_prev, W_ih, W_hh, gates);
    k_lstm<<<256, 256, 0, stream>>>(gates, b_ih, b_hh, c_prev, cbuf, hbuf);

    // head params: direct-gather GEMM over the 7 live heads (head 7 is dead)
    k_gemm_head<<<dim3(22, 8), 256, 0, stream>>>(cbuf, Wk, Wbeta, Wg, Ws, Wgam, We, Wa, Chead);
    k_headact<<<896, 256, 0, stream>>>(Chead, bk, bbeta, bg, bs, bgam, be, ba,
                                       keys, knorm, betaA, gA, gammaA, sA, eA, aA);

    // fused addressing chain: 5 sweeps + 4 weight phases, one cooperative launch
    {
        void* margs[] = {
            (void*)&memory, (void*)&wbuf, (void*)&eA, (void*)&aA, (void*)&keys,
            (void*)&knorm, (void*)&sims, (void*)&rbuf, (void*)&prev_weights,
            (void*)&betaA, (void*)&gA, (void*)&gammaA, (void*)&sA
        };
        hipLaunchCooperativeKernel((const void*)k_mega, dim3(g_grid), dim3(256),
                                   (void**)margs, 0, stream);
    }

    // output layer (full-K GEMM fused with bias+sigmoid)
    k_out_full<<<dim3(4, 2), 256, 0, stream>>>(hbuf, rbuf, W_out, b_out, (float*)d_out);

    (void)in_sizes; (void)n_in; (void)out_size; (void)ws_size;
}

// Round 3
// 527.464 us; speedup vs baseline: 2.1286x; 2.1286x over previous
//
#include <hip/hip_runtime.h>
#include <math.h>

#define BSZ 128
#define NN_ 4096
#define MM_ 64
#define HH_ 512
#define EPSF 1e-8f

__device__ __forceinline__ float sigmoidf_(float x) { return 1.0f / (1.0f + expf(-x)); }
__device__ __forceinline__ float softplusf_(float x) { return fmaxf(x, 0.0f) + log1pf(expf(-fabsf(x))); }

// ------------------------------------------------------------------
// gatesP[z][128,2048] = [in_data|prev_reads|h_prev][128,1024] @ [W_ih|W_hh][2048,1024]^T
// split-K=4 into separate partial buffers (NO atomics, no zero-init)
__global__ __launch_bounds__(256) void k_gemm_gates(const float* __restrict__ in_data,
                                                    const float* __restrict__ prev_reads,
                                                    const float* __restrict__ h_prev,
                                                    const float* __restrict__ W_ih,
                                                    const float* __restrict__ W_hh,
                                                    float* __restrict__ Cp) {
    __shared__ float Alds[64 * 65];
    __shared__ float Wlds[64 * 65];
    int t = threadIdx.x;
    int n0 = blockIdx.x * 64;
    int b0 = blockIdx.y * 64;
    float* C = Cp + (size_t)blockIdx.z * (BSZ * 2048);
    int ob = (t & 15) * 4;
    int bb = (t >> 4) * 4;
    float acc[4][4];
#pragma unroll
    for (int i = 0; i < 4; ++i)
#pragma unroll
        for (int j = 0; j < 4; ++j) acc[i][j] = 0.f;
    for (int kt = 0; kt < 4; ++kt) {
        int k0 = blockIdx.z * 256 + kt * 64;
        __syncthreads();
        for (int i = 0; i < 4; ++i) {
            int f = t + 256 * i;
            int row = f >> 4, kk = (f & 15) * 4;
            int k = k0 + kk;
            float4 v;
            if (k < 256) v = *(const float4*)(in_data + ((b0 + row) << 8) + k);
            else if (k < 512) {
                int q = k - 256;
                v = *(const float4*)(prev_reads + (((q >> 6) * BSZ + b0 + row) << 6) + (q & 63));
            } else v = *(const float4*)(h_prev + ((b0 + row) << 9) + (k - 512));
            Alds[(kk + 0) * 65 + row] = v.x;
            Alds[(kk + 1) * 65 + row] = v.y;
            Alds[(kk + 2) * 65 + row] = v.z;
            Alds[(kk + 3) * 65 + row] = v.w;
        }
        for (int i = 0; i < 4; ++i) {
            int f = t + 256 * i;
            int o = f >> 4, kk = (f & 15) * 4;
            int j = n0 + o, k = k0 + kk;
            const float* src = (k < 512) ? (W_ih + (size_t)j * 512 + k)
                                         : (W_hh + (size_t)j * 512 + (k - 512));
            float4 v = *(const float4*)src;
            Wlds[(kk + 0) * 65 + o] = v.x;
            Wlds[(kk + 1) * 65 + o] = v.y;
            Wlds[(kk + 2) * 65 + o] = v.z;
            Wlds[(kk + 3) * 65 + o] = v.w;
        }
        __syncthreads();
        for (int kk = 0; kk < 64; ++kk) {
            const float* wp = &Wlds[kk * 65 + ob];
            const float* ap = &Alds[kk * 65 + bb];
            float w0 = wp[0], w1 = wp[1], w2 = wp[2], w3 = wp[3];
#pragma unroll
            for (int j = 0; j < 4; ++j) {
                float av = ap[j];
                acc[0][j] = fmaf(w0, av, acc[0][j]);
                acc[1][j] = fmaf(w1, av, acc[1][j]);
                acc[2][j] = fmaf(w2, av, acc[2][j]);
                acc[3][j] = fmaf(w3, av, acc[3][j]);
            }
        }
    }
#pragma unroll
    for (int i = 0; i < 4; ++i)
#pragma unroll
        for (int j = 0; j < 4; ++j)
            C[(size_t)(b0 + bb + j) * 2048 + n0 + ob + i] = acc[i][j];
}

// ------------------------------------------------------------------
// LSTM pointwise, summing the 4 gate partials
__global__ void k_lstm(const float* __restrict__ gatesP, const float* __restrict__ b_ih,
                       const float* __restrict__ b_hh, const float* __restrict__ c_prev,
                       float* __restrict__ cbuf, float* __restrict__ hbuf) {
    int idx = blockIdx.x * blockDim.x + threadIdx.x;
    if (idx >= BSZ * HH_) return;
    int b = idx >> 9, j = idx & 511;
    float gi = b_ih[j]        + b_hh[j];
    float gf = b_ih[512 + j]  + b_hh[512 + j];
    float gg = b_ih[1024 + j] + b_hh[1024 + j];
    float go = b_ih[1536 + j] + b_hh[1536 + j];
#pragma unroll
    for (int p = 0; p < 4; ++p) {
        const float* gr = gatesP + (size_t)p * (BSZ * 2048) + (size_t)b * 2048;
        gi += gr[j];
        gf += gr[512 + j];
        gg += gr[1024 + j];
        go += gr[1536 + j];
    }
    float cc = sigmoidf_(gf) * c_prev[idx] + sigmoidf_(gi) * tanhf(gg);
    float hh = sigmoidf_(go) * tanhf(cc);
    cbuf[idx] = cc;
    hbuf[idx] = hh;
}

// ------------------------------------------------------------------
// CheadP[z][128,1408] = cbuf[128,512] @ Whead[1408,512]^T  (split-K=2, partials,
// rows gathered from the 7 live heads' parameter arrays; rows >=1386 zero pad)
__device__ __forceinline__ const float* whead_row_ptr(const float* Wk, const float* Wbeta,
                                                      const float* Wg, const float* Ws,
                                                      const float* Wgam, const float* We,
                                                      const float* Wa, int r) {
    int i = r / 198, q = r - i * 198;
    if (q < 64)  return Wk + (size_t)((i << 6) + q) * 512;
    if (q == 64) return Wbeta + (size_t)i * 512;
    if (q == 65) return Wg + (size_t)i * 512;
    if (q <= 68) return Ws + (size_t)(i * 3 + q - 66) * 512;
    if (q == 69) return Wgam + (size_t)i * 512;
    if (q < 134) return We + (size_t)((i << 6) + q - 70) * 512;
    return Wa + (size_t)((i << 6) + q - 134) * 512;
}

__global__ __launch_bounds__(256) void k_gemm_head(const float* __restrict__ A,
                                                   const float* __restrict__ Wk,
                                                   const float* __restrict__ Wbeta,
                                                   const float* __restrict__ Wg,
                                                   const float* __restrict__ Ws,
                                                   const float* __restrict__ Wgam,
                                                   const float* __restrict__ We,
                                                   const float* __restrict__ Wa,
                                                   float* __restrict__ Cp) {
    __shared__ float Alds[64 * 65];
    __shared__ float Wlds[64 * 65];
    int t = threadIdx.x;
    int n0 = blockIdx.x * 64;
    int b0 = blockIdx.y * 64;
    float* C = Cp + (size_t)blockIdx.z * (BSZ * 1408);
    int ob = (t & 15) * 4;
    int bb = (t >> 4) * 4;
    float acc[4][4];
#pragma unroll
    for (int i = 0; i < 4; ++i)
#pragma unroll
        for (int j = 0; j < 4; ++j) acc[i][j] = 0.f;
    for (int kt = 0; kt < 4; ++kt) {
        int k0 = blockIdx.z * 256 + kt * 64;
        __syncthreads();
        for (int i = 0; i < 4; ++i) {
            int f = t + 256 * i;
            int row = f >> 4, kk = (f & 15) * 4;
            float4 v = *(const float4*)(A + (size_t)(b0 + row) * 512 + k0 + kk);
            Alds[(kk + 0) * 65 + row] = v.x;
            Alds[(kk + 1) * 65 + row] = v.y;
            Alds[(kk + 2) * 65 + row] = v.z;
            Alds[(kk + 3) * 65 + row] = v.w;
        }
        for (int i = 0; i < 4; ++i) {
            int f = t + 256 * i;
            int o = f >> 4, kk = (f & 15) * 4;
            int r = n0 + o;
            float4 v = make_float4(0.f, 0.f, 0.f, 0.f);
            if (r < 1386) {
                const float* p = whead_row_ptr(Wk, Wbeta, Wg, Ws, Wgam, We, Wa, r) + k0 + kk;
                v = *(const float4*)p;
            }
            Wlds[(kk + 0) * 65 + o] = v.x;
            Wlds[(kk + 1) * 65 + o] = v.y;
            Wlds[(kk + 2) * 65 + o] = v.z;
            Wlds[(kk + 3) * 65 + o] = v.w;
        }
        __syncthreads();
        for (int kk = 0; kk < 64; ++kk) {
            const float* wp = &Wlds[kk * 65 + ob];
            const float* ap = &Alds[kk * 65 + bb];
            float w0 = wp[0], w1 = wp[1], w2 = wp[2], w3 = wp[3];
#pragma unroll
            for (int j = 0; j < 4; ++j) {
                float av = ap[j];
                acc[0][j] = fmaf(w0, av, acc[0][j]);
                acc[1][j] = fmaf(w1, av, acc[1][j]);
                acc[2][j] = fmaf(w2, av, acc[2][j]);
                acc[3][j] = fmaf(w3, av, acc[3][j]);
            }
        }
    }
#pragma unroll
    for (int i = 0; i < 4; ++i)
#pragma unroll
        for (int j = 0; j < 4; ++j)
            C[(size_t)(b0 + bb + j) * 1408 + n0 + ob + i] = acc[i][j];
}

// ------------------------------------------------------------------
// per (head<7, b): sum 2 partials + bias + activations
__global__ __launch_bounds__(256) void k_headact(const float* __restrict__ C0,
                                                 const float* __restrict__ C1,
                                                 const float* __restrict__ bk, const float* __restrict__ bbeta,
                                                 const float* __restrict__ bg, const float* __restrict__ bs,
                                                 const float* __restrict__ bgam, const float* __restrict__ be,
                                                 const float* __restrict__ ba,
                                                 float* __restrict__ keys, float* __restrict__ knorm,
                                                 float* __restrict__ betaA, float* __restrict__ gA,
                                                 float* __restrict__ gammaA, float* __restrict__ sA,
                                                 float* __restrict__ eA, float* __restrict__ aA) {
    __shared__ float sk[64];
    __shared__ float s3[3];
    int blk = blockIdx.x;
    int i = blk >> 7, b = blk & 127;
    int q = threadIdx.x;
    float val = 0.f;
    if (q < 198) {
        float bv = (q < 64)   ? bk[(i << 6) + q]
                 : (q == 64)  ? bbeta[i]
                 : (q == 65)  ? bg[i]
                 : (q <= 68)  ? bs[i * 3 + q - 66]
                 : (q == 69)  ? bgam[i]
                 : (q < 134)  ? be[(i << 6) + q - 70]
                              : ba[(i << 6) + q - 134];
        size_t idx = (size_t)b * 1408 + i * 198 + q;
        val = C0[idx] + C1[idx] + bv;
    }
    if (q < 64) { keys[(size_t)(i * BSZ + b) * 64 + q] = val; sk[q] = val * val; }
    if (q >= 66 && q <= 68) s3[q - 66] = val;
    __syncthreads();
    if (q == 0) {
        float s = 0.f;
        for (int m2 = 0; m2 < 64; ++m2) s += sk[m2];
        knorm[i * BSZ + b] = sqrtf(s);
    }
    if (q == 64) betaA[i * BSZ + b] = softplusf_(val);
    if (q == 65) gA[i * BSZ + b] = sigmoidf_(val);
    if (q == 69) gammaA[i * BSZ + b] = 1.f + softplusf_(val);
    if (q == 66) {
        float mx = fmaxf(s3[0], fmaxf(s3[1], s3[2]));
        float e0 = expf(s3[0] - mx), e1 = expf(s3[1] - mx), e2 = expf(s3[2] - mx);
        float inv = 1.f / (e0 + e1 + e2);
        sA[(i * BSZ + b) * 3 + 0] = e0 * inv;
        sA[(i * BSZ + b) * 3 + 1] = e1 * inv;
        sA[(i * BSZ + b) * 3 + 2] = e2 * inv;
    }
    if (q >= 70 && q < 134)  eA[(size_t)(i * BSZ + b) * 64 + (q - 70)] = sigmoidf_(val);
    if (q >= 134 && q < 198) aA[(size_t)(i * BSZ + b) * 64 + (q - 134)] = tanhf(val);
}

// ------------------------------------------------------------------
// READ-ONLY sweep over pristine mem0. Reconstructs updated memory states in
// registers from write weights w1/w3/w5 + per-batch e/a vectors. Computes up
// to 2 sims on state `napply`, and a read-accumulate on state `read_state`.
// grid = B*N/64 blocks of 256; 16 lanes per row (float4 per lane)
__global__ __launch_bounds__(256) void k_pass2(const float* __restrict__ mem,
                                               const float* __restrict__ wbuf,
                                               const float* __restrict__ eA, const float* __restrict__ aA,
                                               const float* __restrict__ keys, const float* __restrict__ knorm,
                                               float* __restrict__ sims, float* __restrict__ r_out,
                                               int napply, int nsims, int sh0, int sh1,
                                               int read_state, int read_head, int read_idx) {
    __shared__ __align__(16) float rbuf[16][64];
    int t = threadIdx.x;
    int lane = t & 15, grp = t >> 4;
    int base = blockIdx.x * 64;       // 64 consecutive rows, same b
    int b = base >> 12;
    int m4 = lane * 4;
    float4 e1 = *(const float4*)(eA + (size_t)(1 * BSZ + b) * 64 + m4);
    float4 a1 = *(const float4*)(aA + (size_t)(1 * BSZ + b) * 64 + m4);
    float4 e3 = *(const float4*)(eA + (size_t)(3 * BSZ + b) * 64 + m4);
    float4 a3 = *(const float4*)(aA + (size_t)(3 * BSZ + b) * 64 + m4);
    float4 e5 = *(const float4*)(eA + (size_t)(5 * BSZ + b) * 64 + m4);
    float4 a5 = *(const float4*)(aA + (size_t)(5 * BSZ + b) * 64 + m4);
    float4 k0v = make_float4(0.f, 0.f, 0.f, 0.f), k1v = k0v;
    float kn0v = 0.f, kn1v = 0.f;
    if (nsims > 0) { k0v = *(const float4*)(keys + (size_t)(sh0 * BSZ + b) * 64 + m4); kn0v = knorm[sh0 * BSZ + b]; }
    if (nsims > 1) { k1v = *(const float4*)(keys + (size_t)(sh1 * BSZ + b) * 64 + m4); kn1v = knorm[sh1 * BSZ + b]; }
    const float* w1p = wbuf + (size_t)1 * BSZ * NN_;
    const float* w3p = wbuf + (size_t)3 * BSZ * NN_;
    const float* w5p = wbuf + (size_t)5 * BSZ * NN_;
    const float* wrp = (read_head >= 0) ? (wbuf + (size_t)read_head * BSZ * NN_) : nullptr;
    float* sim0 = sims + (size_t)sh0 * BSZ * NN_;
    float* sim1 = sims + (size_t)sh1 * BSZ * NN_;

    float4 racc = make_float4(0.f, 0.f, 0.f, 0.f);
    for (int it = 0; it < 4; ++it) {
        int row = base + it * 16 + grp;
        float4 m = *(const float4*)(mem + (size_t)row * 64 + m4);
        float4 mr = m;
        if (napply >= 1) {
            float w = w1p[row];
            m.x = m.x * (1.f - w * e1.x) + w * a1.x;
            m.y = m.y * (1.f - w * e1.y) + w * a1.y;
            m.z = m.z * (1.f - w * e1.z) + w * a1.z;
            m.w = m.w * (1.f - w * e1.w) + w * a1.w;
            if (read_state == 1) mr = m;
        }
        if (napply >= 2) {
            float w = w3p[row];
            m.x = m.x * (1.f - w * e3.x) + w * a3.x;
            m.y = m.y * (1.f - w * e3.y) + w * a3.y;
            m.z = m.z * (1.f - w * e3.z) + w * a3.z;
            m.w = m.w * (1.f - w * e3.w) + w * a3.w;
            if (read_state == 2) mr = m;
        }
        if (napply >= 3) {
            float w = w5p[row];
            m.x = m.x * (1.f - w * e5.x) + w * a5.x;
            m.y = m.y * (1.f - w * e5.y) + w * a5.y;
            m.z = m.z * (1.f - w * e5.z) + w * a5.z;
            m.w = m.w * (1.f - w * e5.w) + w * a5.w;
            if (read_state == 3) mr = m;
        }
        if (read_head >= 0) {
            float wr = wrp[row];
            racc.x = fmaf(wr, mr.x, racc.x);
            racc.y = fmaf(wr, mr.y, racc.y);
            racc.z = fmaf(wr, mr.z, racc.z);
            racc.w = fmaf(wr, mr.w, racc.w);
        }
        if (nsims > 0) {
            float d0 = m.x * k0v.x + m.y * k0v.y + m.z * k0v.z + m.w * k0v.w;
            float nn = m.x * m.x + m.y * m.y + m.z * m.z + m.w * m.w;
            float d1 = 0.f;
            if (nsims > 1) d1 = m.x * k1v.x + m.y * k1v.y + m.z * k1v.z + m.w * k1v.w;
#pragma unroll
            for (int off = 8; off >= 1; off >>= 1) {
                d0 += __shfl_xor(d0, off, 16);
                nn += __shfl_xor(nn, off, 16);
                if (nsims > 1) d1 += __shfl_xor(d1, off, 16);
            }
            if (lane == 0) {
                float nm = sqrtf(nn);
                sim0[row] = d0 / (nm * kn0v + EPSF);
                if (nsims > 1) sim1[row] = d1 / (nm * kn1v + EPSF);
            }
        }
    }
    if (read_head >= 0) {
        *(float4*)(&rbuf[grp][m4]) = racc;
        __syncthreads();
        if (t < 64) {
            float s = 0.f;
#pragma unroll
            for (int g2 = 0; g2 < 16; ++g2) s += rbuf[g2][t];
            atomicAdd(&r_out[(size_t)(read_idx * BSZ + b) * 64 + t], s);
        }
    }
}

// ------------------------------------------------------------------
// per (head, b): softmax(beta*sim) -> interpolate -> shift -> sharpen -> normalize
// 1024 threads, 4 elems/thread, wave-shuffle reductions (4 barriers total)
__global__ __launch_bounds__(1024) void k_weights(const float* __restrict__ sims,
                                                  const float* __restrict__ prev_w,
                                                  const float* __restrict__ betaA, const float* __restrict__ gA,
                                                  const float* __restrict__ gammaA, const float* __restrict__ sA,
                                                  float* __restrict__ wout_base, int head0) {
    __shared__ float wg[NN_];
    __shared__ float redm[16], reds[16], redp[16];
    int h = head0 + blockIdx.y, b = blockIdx.x;
    int hb = h * BSZ + b;
    float beta = betaA[hb], g = gA[hb], gamma = gammaA[hb];
    float s0 = sA[hb * 3 + 0], s1 = sA[hb * 3 + 1], s2 = sA[hb * 3 + 2];
    const float* sim = sims + (size_t)hb * NN_;
    const float* pw = prev_w + (size_t)hb * NN_;
    float* wout = wout_base + (size_t)hb * NN_;
    int t = threadIdx.x, wv = t >> 6, ln = t & 63;
    float tv[4];
    float lmax = -3.4e38f;
#pragma unroll
    for (int j = 0; j < 4; ++j) {
        float x = beta * sim[t + 1024 * j];
        tv[j] = x;
        lmax = fmaxf(lmax, x);
    }
#pragma unroll
    for (int off = 32; off >= 1; off >>= 1) lmax = fmaxf(lmax, __shfl_xor(lmax, off));
    if (ln == 0) redm[wv] = lmax;
    __syncthreads();
    float Mx = redm[0];
#pragma unroll
    for (int k = 1; k < 16; ++k) Mx = fmaxf(Mx, redm[k]);
    float lsum = 0.f;
#pragma unroll
    for (int j = 0; j < 4; ++j) { float ex = expf(tv[j] - Mx); tv[j] = ex; lsum += ex; }
#pragma unroll
    for (int off = 32; off >= 1; off >>= 1) lsum += __shfl_xor(lsum, off);
    if (ln == 0) reds[wv] = lsum;
    __syncthreads();
    float S = 0.f;
#pragma unroll
    for (int k = 0; k < 16; ++k) S += reds[k];
    float invS = 1.f / S;
#pragma unroll
    for (int j = 0; j < 4; ++j) {
        int n = t + 1024 * j;
        wg[n] = g * tv[j] * invS + (1.f - g) * pw[n];
    }
    __syncthreads();
    float lsum2 = 0.f;
#pragma unroll
    for (int j = 0; j < 4; ++j) {
        int n = t + 1024 * j;
        float wsft = s0 * wg[(n + 1) & (NN_ - 1)] + s1 * wg[n] + s2 * wg[(n - 1) & (NN_ - 1)];
        float wp = powf(wsft, gamma);
        tv[j] = wp;
        lsum2 += wp;
    }
#pragma unroll
    for (int off = 32; off >= 1; off >>= 1) lsum2 += __shfl_xor(lsum2, off);
    if (ln == 0) redp[wv] = lsum2;
    __syncthreads();
    float S2 = 0.f;
#pragma unroll
    for (int k = 0; k < 16; ++k) S2 += redp[k];
    float inv2 = 1.f / (S2 + EPSF);
#pragma unroll
    for (int j = 0; j < 4; ++j) wout[t + 1024 * j] = tv[j] * inv2;
}

// ------------------------------------------------------------------
// out[128,256] = sigmoid([hbuf|rbuf][128,768] @ W_out[256,768]^T + b_out)
// full-K (no atomics): grid = (4 n-tiles, 2 b-tiles)
__global__ __launch_bounds__(256) void k_out_full(const float* __restrict__ hbuf,
                                                  const float* __restrict__ rbuf,
                                                  const float* __restrict__ W_out,
                                                  const float* __restrict__ b_out,
                                                  float* __restrict__ out) {
    __shared__ float Alds[64 * 65];
    __shared__ float Wlds[64 * 65];
    int t = threadIdx.x;
    int n0 = blockIdx.x * 64;
    int b0 = blockIdx.y * 64;
    int ob = (t & 15) * 4;
    int bb = (t >> 4) * 4;
    float acc[4][4];
#pragma unroll
    for (int i = 0; i < 4; ++i)
#pragma unroll
        for (int j = 0; j < 4; ++j) acc[i][j] = 0.f;
    for (int k0 = 0; k0 < 768; k0 += 64) {
        __syncthreads();
        for (int i = 0; i < 4; ++i) {
            int f = t + 256 * i;
            int rb = f >> 4, kk = (f & 15) * 4;
            int k = k0 + kk;
            float4 v;
            if (k < 512) v = *(const float4*)(hbuf + ((b0 + rb) << 9) + k);
            else {
                int q = k - 512;
                v = *(const float4*)(rbuf + (((q >> 6) * BSZ + b0 + rb) << 6) + (q & 63));
            }
            Alds[(kk + 0) * 65 + rb] = v.x;
            Alds[(kk + 1) * 65 + rb] = v.y;
            Alds[(kk + 2) * 65 + rb] = v.z;
            Alds[(kk + 3) * 65 + rb] = v.w;
        }
        for (int i = 0; i < 4; ++i) {
            int f = t + 256 * i;
            int o = f >> 4, kk = (f & 15) * 4;
            float4 v = *(const float4*)(W_out + (size_t)(n0 + o) * 768 + k0 + kk);
            Wlds[(kk + 0) * 65 + o] = v.x;
            Wlds[(kk + 1) * 65 + o] = v.y;
            Wlds[(kk + 2) * 65 + o] = v.z;
            Wlds[(kk + 3) * 65 + o] = v.w;
        }
        __syncthreads();
        for (int kk = 0; kk < 64; ++kk) {
            const float* wp = &Wlds[kk * 65 + ob];
            const float* ap = &Alds[kk * 65 + bb];
            float w0 = wp[0], w1 = wp[1], w2 = wp[2], w3 = wp[3];
#pragma unroll
            for (int j = 0; j < 4; ++j) {
                float av = ap[j];
                acc[0][j] = fmaf(w0, av, acc[0][j]);
                acc[1][j] = fmaf(w1, av, acc[1][j]);
                acc[2][j] = fmaf(w2, av, acc[2][j]);
                acc[3][j] = fmaf(w3, av, acc[3][j]);
            }
        }
    }
#pragma unroll
    for (int i = 0; i < 4; ++i)
#pragma unroll
        for (int j = 0; j < 4; ++j)
            out[(size_t)(b0 + bb + j) * 256 + n0 + ob + i] = sigmoidf_(acc[i][j] + b_out[n0 + ob + i]);
}

// ------------------------------------------------------------------
extern "C" void kernel_launch(void* const* d_in, const int* in_sizes, int n_in,
                              void* d_out, int out_size, void* d_ws, size_t ws_size,
                              hipStream_t stream) {
    const float* in_data      = (const float*)d_in[0];
    const float* memory       = (const float*)d_in[1];   // READ-ONLY
    const float* h_prev       = (const float*)d_in[2];
    const float* c_prev       = (const float*)d_in[3];
    const float* prev_reads   = (const float*)d_in[4];
    const float* prev_weights = (const float*)d_in[5];
    const float* W_ih = (const float*)d_in[6];
    const float* b_ih = (const float*)d_in[7];
    const float* W_hh = (const float*)d_in[8];
    const float* b_hh = (const float*)d_in[9];
    const float* W_out = (const float*)d_in[10];
    const float* b_out = (const float*)d_in[11];
    const float* Wk   = (const float*)d_in[12];
    const float* bk   = (const float*)d_in[13];
    const float* Wbeta = (const float*)d_in[14];
    const float* bbeta = (const float*)d_in[15];
    const float* Wg   = (const float*)d_in[16];
    const float* bg   = (const float*)d_in[17];
    const float* Ws   = (const float*)d_in[18];
    const float* bs   = (const float*)d_in[19];
    const float* Wgam = (const float*)d_in[20];
    const float* bgam = (const float*)d_in[21];
    const float* We   = (const float*)d_in[22];
    const float* be   = (const float*)d_in[23];
    const float* Wa   = (const float*)d_in[24];
    const float* ba   = (const float*)d_in[25];

    float* ws = (float*)d_ws;
    // zero-init region: only rbuf (atomic read accumulator)
    size_t o_r      = 0;                          // [4,128,64] = 32768
    size_t zero_floats = 32768;                   // 128 KB
    size_t o_gatesP = zero_floats;                // 4 x [128,2048] = 1048576
    size_t o_cheadP = o_gatesP + 1048576;         // 2 x [128,1408] = 360448
    size_t o_c     = o_cheadP + 360448;           // [128,512]
    size_t o_h     = o_c + 65536;                 // [128,512]
    size_t o_keys  = o_h + 65536;                 // [7,128,64] = 57344
    size_t o_knorm = o_keys + 57344;              // [7,128] pad 1024
    size_t o_beta  = o_knorm + 1024;
    size_t o_g     = o_beta + 1024;
    size_t o_gamma = o_g + 1024;
    size_t o_s     = o_gamma + 1024;              // [7,128,3] pad 3072
    size_t o_e     = o_s + 3072;                  // [7,128,64] = 57344
    size_t o_a     = o_e + 57344;
    size_t o_sims  = o_a + 57344;                 // [7,128,4096] = 3670016
    size_t o_w     = o_sims + 3670016;            // [7,128,4096] = 3670016

    float* rbuf   = ws + o_r;
    float* gatesP = ws + o_gatesP;
    float* CheadP = ws + o_cheadP;
    float* cbuf   = ws + o_c;
    float* hbuf   = ws + o_h;
    float* keys   = ws + o_keys;
    float* knorm  = ws + o_knorm;
    float* betaA  = ws + o_beta;
    float* gA     = ws + o_g;
    float* gammaA = ws + o_gamma;
    float* sA     = ws + o_s;
    float* eA     = ws + o_e;
    float* aA     = ws + o_a;
    float* sims   = ws + o_sims;
    float* wbuf   = ws + o_w;

    hipMemsetAsync(d_ws, 0, zero_floats * sizeof(float), stream);

    // controller LSTM: split-K=4 partial GEMM (no atomics) + pointwise sum
    k_gemm_gates<<<dim3(32, 2, 4), 256, 0, stream>>>(in_data, prev_reads, h_prev, W_ih, W_hh, gatesP);
    k_lstm<<<256, 256, 0, stream>>>(gatesP, b_ih, b_hh, c_prev, cbuf, hbuf);

    // head params: split-K=2 partial GEMM over the 7 live heads (head 7 dead)
    k_gemm_head<<<dim3(22, 2, 2), 256, 0, stream>>>(cbuf, Wk, Wbeta, Wg, Ws, Wgam, We, Wa, CheadP);
    k_headact<<<896, 256, 0, stream>>>(CheadP, CheadP + (size_t)BSZ * 1408,
                                       bk, bbeta, bg, bs, bgam, be, ba,
                                       keys, knorm, betaA, gA, gammaA, sA, eA, aA);

    const int PB = BSZ * NN_ / 64;  // 8192 blocks per sweep
    // S0: sims heads 0,1 on mem0
    k_pass2<<<PB, 256, 0, stream>>>(memory, wbuf, eA, aA, keys, knorm, sims, rbuf,
                                    0, 2, 0, 1, -1, -1, 0);
    k_weights<<<dim3(128, 2), 1024, 0, stream>>>(sims, prev_weights, betaA, gA, gammaA, sA, wbuf, 0);
    // S1: sims heads 2,3 on mem1 (apply w1); r0 from mem0
    k_pass2<<<PB, 256, 0, stream>>>(memory, wbuf, eA, aA, keys, knorm, sims, rbuf,
                                    1, 2, 2, 3, 0, 0, 0);
    k_weights<<<dim3(128, 2), 1024, 0, stream>>>(sims, prev_weights, betaA, gA, gammaA, sA, wbuf, 2);
    // S2: sims heads 4,5 on mem2 (apply w1,w3); r2 from mem1
    k_pass2<<<PB, 256, 0, stream>>>(memory, wbuf, eA, aA, keys, knorm, sims, rbuf,
                                    2, 2, 4, 5, 1, 2, 1);
    k_weights<<<dim3(128, 2), 1024, 0, stream>>>(sims, prev_weights, betaA, gA, gammaA, sA, wbuf, 4);
    // S3: sim head 6 on mem3 (apply w1,w3,w5); r4 from mem2
    k_pass2<<<PB, 256, 0, stream>>>(memory, wbuf, eA, aA, keys, knorm, sims, rbuf,
                                    3, 1, 6, 6, 2, 4, 2);
    k_weights<<<dim3(128, 1), 1024, 0, stream>>>(sims, prev_weights, betaA, gA, gammaA, sA, wbuf, 6);
    // S4: r6 from mem3; head 7 dead
    k_pass2<<<PB, 256, 0, stream>>>(memory, wbuf, eA, aA, keys, knorm, sims, rbuf,
                                    3, 0, 0, 0, 3, 6, 3);

    // output layer (full-K GEMM fused with bias+sigmoid)
    k_out_full<<<dim3(4, 2), 256, 0, stream>>>(hbuf, rbuf, W_out, b_out, (float*)d_out);

    (void)in_sizes; (void)n_in; (void)out_size; (void)ws_size;
}